// Round 3
// baseline (65.875 us; speedup 1.0000x reference)
//
#include <hip/hip_runtime.h>
#include <math.h>

// PLCC loss: masked (labels==2) pairwise InfoNCE + continuity.
// Compact masked rows (L ~ 2731 of 8192), normalize features, store
// transposed fnT[k][slot]; tiled L x L pairwise kernel (128x128 per block,
// 8x8 micro-tile, f32 VALU outer product); deterministic reductions.
//
// Diagonal pairs are a knife edge: exp(10*sim_ii)=e^10 dominates row sums and
// ref's f32 sq_ii = 2*(s - g) is a +-1ulp coin flip. Reference (XLA-CPU-style)
// semantics reconstructed from measured net-flip counts:
//   s = r(r(p0+p1)+p2)            (sq_norm: rounded products, sequential sum)
//   g = r(r(p0+p2)+p1)            (dot K=3 padded to 4, SIMD halving tree)
//   diag is "pos" iff s - g > 5e-13   (Sterbenz: 2*(s-g) exact vs 1e-12)

#define NPTS 8192
#define DIM 64
#define TILE 128
#define CHUNKS 16
#define MAXT (NPTS / TILE) /* 64 */

// workspace layout (bytes)
#define OFF_L 0
#define OFF_IDX 1024
#define OFF_FNT (OFF_IDX + NPTS * 4)          /* fnT[DIM][NPTS] floats */
#define OFF_CS (OFF_FNT + DIM * NPTS * 4)     /* float4[NPTS]: c0,c1,c2,|c|^2 */
#define OFF_PP (OFF_CS + NPTS * 16)           /* float[CHUNKS][NPTS] pos partials */
#define OFF_PN (OFF_PP + CHUNKS * NPTS * 4)   /* float[CHUNKS][NPTS] neg partials */
#define OFF_CT (OFF_PN + CHUNKS * NPTS * 4)   /* float[MAXT*CHUNKS] cont partials */
#define OFF_DF (OFF_CT + MAXT * CHUNKS * 4)   /* int[NPTS] diag-pos flags */
// total ~3.39 MB

__global__ __launch_bounds__(1024) void k_scan(const int* __restrict__ labels,
                                               int* __restrict__ idx,
                                               int* __restrict__ Lout) {
  __shared__ int sc[1024];
  __shared__ int wres[16];
  const int t = threadIdx.x;
  const int base = t * 8;
  int w[8];
#pragma unroll
  for (int j = 0; j < 8; j++) w[j] = labels[base + j];
  // int64-shipped-labels detection: values in {0,1,2} => if dtype is int64
  // (little-endian), every odd 32-bit word is 0.
  int oddz = (w[1] == 0) && (w[3] == 0) && (w[5] == 0) && (w[7] == 0);
  unsigned long long wa = __ballot(!oddz);
  if ((t & 63) == 0) wres[t >> 6] = (wa == 0ull);
  __syncthreads();
  int is64 = 1;
#pragma unroll
  for (int i = 0; i < 16; i++) is64 &= wres[i];

  int bits = 0, cnt = 0;
  if (is64) {
    const long long* l64 = (const long long*)labels;
#pragma unroll
    for (int j = 0; j < 8; j++) {
      bool f = (l64[base + j] == 2ll);
      bits |= ((int)f) << j;
      cnt += (int)f;
    }
  } else {
#pragma unroll
    for (int j = 0; j < 8; j++) {
      bool f = (w[j] == 2);
      bits |= ((int)f) << j;
      cnt += (int)f;
    }
  }
  sc[t] = cnt;
  __syncthreads();
  for (int off = 1; off < 1024; off <<= 1) {
    int v = 0;
    if (t >= off) v = sc[t - off];
    __syncthreads();
    sc[t] += v;
    __syncthreads();
  }
  int pos = sc[t] - cnt;  // exclusive prefix
#pragma unroll
  for (int j = 0; j < 8; j++) {
    if (bits & (1 << j)) idx[pos++] = base + j;
  }
  if (t == 1023) *Lout = sc[1023];
}

// one wave per compact slot: normalize features, gather coords, diag flag
__global__ __launch_bounds__(256) void k_gather(const float* __restrict__ feats,
                                                const float* __restrict__ coords,
                                                const int* __restrict__ idx,
                                                const int* __restrict__ Lp,
                                                float* __restrict__ fnT,
                                                float4* __restrict__ cs,
                                                int* __restrict__ diagf) {
  const int L = *Lp;
  const int gw = (int)((blockIdx.x * blockDim.x + threadIdx.x) >> 6);
  const int lane = threadIdx.x & 63;
  if (gw >= L) return;
  const int row = idx[gw];
  float f = feats[row * DIM + lane];
  float ss = f * f;
#pragma unroll
  for (int m = 32; m; m >>= 1) ss += __shfl_xor(ss, m);
  float nrm = fmaxf(sqrtf(ss), 1e-8f);
  fnT[lane * NPTS + gw] = f / nrm;  // transposed store
  if (lane == 0) {
    float c0 = coords[row * 3 + 0];
    float c1 = coords[row * 3 + 1];
    float c2 = coords[row * 3 + 2];
    // ref diagonal semantics: rounded products; s = sequential sum,
    // g = SIMD halving-tree sum ((p0+p2)+p1); pos iff s - g > 5e-13
    float p0 = __fmul_rn(c0, c0);
    float p1 = __fmul_rn(c1, c1);
    float p2 = __fmul_rn(c2, c2);
    float s = __fadd_rn(__fadd_rn(p0, p1), p2);
    float g = __fadd_rn(__fadd_rn(p0, p2), p1);
    diagf[gw] = (__fadd_rn(s, -g) > 5e-13f) ? 1 : 0;
    cs[gw] = make_float4(c0, c1, c2, c0 * c0 + c1 * c1 + c2 * c2);
  }
}

__global__ __launch_bounds__(256) void k_pair(const float* __restrict__ fnT,
                                              const float4* __restrict__ cs,
                                              const int* __restrict__ Lp,
                                              const int* __restrict__ diagf,
                                              float* __restrict__ pp,
                                              float* __restrict__ pn,
                                              float* __restrict__ contp) {
  __shared__ float Ak[DIM][TILE];
  __shared__ float Bk[DIM][TILE];
  __shared__ float cred[4];

  const int L = *Lp;
  const int nT = (L + TILE - 1) / TILE;
  const int bi = blockIdx.x, ch = blockIdx.y;
  const int bid = bi * CHUNKS + ch;
  const int t = threadIdx.x;

  if (bi >= nT) {
    if (t == 0) contp[bid] = 0.f;
    return;
  }

  const int rb = bi * TILE;
  const int tr = t >> 4;  // 0..15 -> row group (4 rows, x2 halves)
  const int tc = t & 15;  // 0..15 -> col group (4 cols, x2 halves)

  // ---- stage A tile: Ak[k][r] from fnT[k][rb+r], zero-fill r>=L ----
#pragma unroll
  for (int i = 0; i < 8; i++) {
    int q = t + 256 * i;  // 0..2047 float4 units
    int k = q >> 5;       // 0..63
    int c0 = (q & 31) * 4;
    float4 v = *(const float4*)&fnT[k * NPTS + rb + c0];
    if (rb + c0 + 0 >= L) v.x = 0.f;
    if (rb + c0 + 1 >= L) v.y = 0.f;
    if (rb + c0 + 2 >= L) v.z = 0.f;
    if (rb + c0 + 3 >= L) v.w = 0.f;
    *(float4*)&Ak[k][c0] = v;
  }

  // per-thread row coords + diag flags (rows: h*64 + tr*4 + ri)
  float4 ca[2][4];
  int dfr[2][4];
#pragma unroll
  for (int h = 0; h < 2; h++)
#pragma unroll
    for (int ri = 0; ri < 4; ri++) {
      int ig = rb + h * 64 + tr * 4 + ri;
      ca[h][ri] = cs[ig];
      dfr[h][ri] = diagf[ig];
    }

  float pos_r[2][4] = {{0.f, 0.f, 0.f, 0.f}, {0.f, 0.f, 0.f, 0.f}};
  float neg_r[2][4] = {{0.f, 0.f, 0.f, 0.f}, {0.f, 0.f, 0.f, 0.f}};
  float cont = 0.f;

  for (int jt = ch; jt < nT; jt += CHUNKS) {
    const int cb = jt * TILE;
    __syncthreads();  // prior compute done before Bk overwrite
#pragma unroll
    for (int i = 0; i < 8; i++) {
      int q = t + 256 * i;
      int k = q >> 5;
      int c0 = (q & 31) * 4;
      float4 v = *(const float4*)&fnT[k * NPTS + cb + c0];
      if (cb + c0 + 0 >= L) v.x = 0.f;
      if (cb + c0 + 1 >= L) v.y = 0.f;
      if (cb + c0 + 2 >= L) v.z = 0.f;
      if (cb + c0 + 3 >= L) v.w = 0.f;
      *(float4*)&Bk[k][c0] = v;
    }
    __syncthreads();

    float acc[2][4][2][4];
#pragma unroll
    for (int h = 0; h < 2; h++)
#pragma unroll
      for (int ri = 0; ri < 4; ri++)
#pragma unroll
        for (int g = 0; g < 2; g++)
#pragma unroll
          for (int ci = 0; ci < 4; ci++) acc[h][ri][g][ci] = 0.f;

#pragma unroll 8
    for (int k = 0; k < DIM; k++) {
      float4 a0 = *(const float4*)&Ak[k][tr * 4];
      float4 a1 = *(const float4*)&Ak[k][64 + tr * 4];
      float4 b0 = *(const float4*)&Bk[k][tc * 4];
      float4 b1 = *(const float4*)&Bk[k][64 + tc * 4];
      float av[2][4] = {{a0.x, a0.y, a0.z, a0.w}, {a1.x, a1.y, a1.z, a1.w}};
      float bv[2][4] = {{b0.x, b0.y, b0.z, b0.w}, {b1.x, b1.y, b1.z, b1.w}};
#pragma unroll
      for (int h = 0; h < 2; h++)
#pragma unroll
        for (int ri = 0; ri < 4; ri++)
#pragma unroll
          for (int g = 0; g < 2; g++)
#pragma unroll
            for (int ci = 0; ci < 4; ci++)
              acc[h][ri][g][ci] += av[h][ri] * bv[g][ci];
    }

    // epilogue: exp / distance / masked accumulation
#pragma unroll
    for (int g = 0; g < 2; g++)
#pragma unroll
      for (int ci = 0; ci < 4; ci++) {
        int jg = cb + g * 64 + tc * 4 + ci;
        float4 cbv = cs[jg];
        bool jv = (jg < L);
#pragma unroll
        for (int h = 0; h < 2; h++)
#pragma unroll
          for (int ri = 0; ri < 4; ri++) {
            int ig = rb + h * 64 + tr * 4 + ri;
            bool valid = jv && (ig < L);
            float sim = acc[h][ri][g][ci];
            float4 cav = ca[h][ri];
            float d3 = cav.x * cbv.x + cav.y * cbv.y + cav.z * cbv.z;
            float sq = fmaxf(cav.w + cbv.w - 2.f * d3, 0.f);
            bool within = (sq < 1.0f) && (sq > 1e-12f);
            if (ig == jg) within = (dfr[h][ri] != 0);  // ref diagonal semantics
            float e = __expf(sim * 10.f);
            if (valid) {
              if (within) {
                pos_r[h][ri] += e;
                cont += fabsf(1.f - sim - sqrtf(sq));
              } else {
                neg_r[h][ri] += e;
              }
            }
          }
      }
  }

  // reduce pos/neg across the 16 tc lanes (same wave, low 4 lane bits)
#pragma unroll
  for (int h = 0; h < 2; h++)
#pragma unroll
    for (int ri = 0; ri < 4; ri++) {
      float p = pos_r[h][ri], n = neg_r[h][ri];
#pragma unroll
      for (int m = 1; m < 16; m <<= 1) {
        p += __shfl_xor(p, m);
        n += __shfl_xor(n, m);
      }
      if (tc == 0) {
        int ig = rb + h * 64 + tr * 4 + ri;
        pp[ch * NPTS + ig] = p;
        pn[ch * NPTS + ig] = n;
      }
    }

  // continuity: block reduce
#pragma unroll
  for (int m = 1; m < 64; m <<= 1) cont += __shfl_xor(cont, m);
  if ((t & 63) == 0) cred[t >> 6] = cont;
  __syncthreads();
  if (t == 0) contp[bid] = cred[0] + cred[1] + cred[2] + cred[3];
}

__global__ __launch_bounds__(1024) void k_final(const float* __restrict__ pp,
                                                const float* __restrict__ pn,
                                                const float* __restrict__ contp,
                                                const int* __restrict__ Lp,
                                                float* __restrict__ out) {
  __shared__ float red[32];
  const int L = *Lp;
  const int t = threadIdx.x;
  float accI = 0.f;
  for (int s = t; s < L; s += 1024) {
    float pos = 0.f, neg = 0.f;
#pragma unroll
    for (int c = 0; c < CHUNKS; c++) {
      pos += pp[c * NPTS + s];
      neg += pn[c * NPTS + s];
    }
    accI += -logf(pos / (neg + pos + 1e-6f));
  }
  float accC = contp[t];  // MAXT*CHUNKS == 1024 entries, one per thread
#pragma unroll
  for (int m = 1; m < 64; m <<= 1) {
    accI += __shfl_xor(accI, m);
    accC += __shfl_xor(accC, m);
  }
  if ((t & 63) == 0) {
    red[t >> 6] = accI;
    red[16 + (t >> 6)] = accC;
  }
  __syncthreads();
  if (t == 0) {
    float sI = 0.f, sC = 0.f;
#pragma unroll
    for (int w = 0; w < 16; w++) {
      sI += red[w];
      sC += red[16 + w];
    }
    float fL = (float)L;
    out[0] = sI / fL + 0.5f * (sC / (fL * fL));
  }
}

extern "C" void kernel_launch(void* const* d_in, const int* in_sizes, int n_in,
                              void* d_out, int out_size, void* d_ws, size_t ws_size,
                              hipStream_t stream) {
  const float* features = (const float*)d_in[0];
  const int* labels = (const int*)d_in[1];
  const float* coords = (const float*)d_in[2];

  char* ws = (char*)d_ws;
  int* Lp = (int*)(ws + OFF_L);
  int* idx = (int*)(ws + OFF_IDX);
  float* fnT = (float*)(ws + OFF_FNT);
  float4* cs = (float4*)(ws + OFF_CS);
  float* pp = (float*)(ws + OFF_PP);
  float* pn = (float*)(ws + OFF_PN);
  float* contp = (float*)(ws + OFF_CT);
  int* diagf = (int*)(ws + OFF_DF);
  float* out = (float*)d_out;

  k_scan<<<1, 1024, 0, stream>>>(labels, idx, Lp);
  k_gather<<<(NPTS * 64) / 256, 256, 0, stream>>>(features, coords, idx, Lp, fnT, cs, diagf);
  k_pair<<<dim3(MAXT, CHUNKS), 256, 0, stream>>>(fnT, cs, Lp, diagf, pp, pn, contp);
  k_final<<<1, 1024, 0, stream>>>(pp, pn, contp, Lp, out);
}

// Round 4
// 53.297 us; speedup vs baseline: 1.2360x; 1.2360x over previous
//
#include <hip/hip_runtime.h>
#include <math.h>

// PLCC loss: masked (labels==2) pairwise InfoNCE + continuity.
// Compact masked rows (L ~ 2731), normalize features, store transposed
// fnT[k][slot]; tiled L x L pairwise kernel (64x64 per block, 4x4 micro,
// f32 VALU outer product, 5 blocks/CU); deterministic reductions.
//
// Diagonal pairs: ref's f32 sq_ii = 2*(s - g) is a +-1ulp coin flip between
// sq_norm's sequential sum s = r(r(p0+p1)+p2) and the dot's SIMD halving
// tree g = r(r(p0+p2)+p1) (K=3 padded to 4). diag pos iff s - g > 5e-13.
// (verified: absmax 0.0078 vs threshold 0.0327 in round 3)

#define NPTS 8192
#define DIM 64
#define TILE 64
#define CHUNKS 32
#define GX 64 /* grid.x; block loops bi = bx, bx+GX, ... */
#define NCT (GX * CHUNKS)

// workspace layout (bytes)
#define OFF_L 0
#define OFF_IDX 1024
#define OFF_FNT (OFF_IDX + NPTS * 4)         /* fnT[DIM][NPTS] floats */
#define OFF_CS (OFF_FNT + DIM * NPTS * 4)    /* float4[NPTS]: c0,c1,c2,|c|^2 */
#define OFF_PP (OFF_CS + NPTS * 16)          /* float[CHUNKS][NPTS] pos partials */
#define OFF_PN (OFF_PP + CHUNKS * NPTS * 4)  /* float[CHUNKS][NPTS] neg partials */
#define OFF_CT (OFF_PN + CHUNKS * NPTS * 4)  /* float[NCT] cont partials */
#define OFF_DF (OFF_CT + NCT * 4)            /* int[NPTS] diag-pos flags */
// total ~4.4 MB

__global__ __launch_bounds__(1024) void k_scan(const int* __restrict__ labels,
                                               int* __restrict__ idx,
                                               int* __restrict__ Lout) {
  __shared__ int sc[1024];
  __shared__ int wres[16];
  const int t = threadIdx.x;
  const int base = t * 8;
  int w[8];
#pragma unroll
  for (int j = 0; j < 8; j++) w[j] = labels[base + j];
  // int64-shipped-labels detection: values in {0,1,2} => if dtype is int64
  // (little-endian), every odd 32-bit word is 0.
  int oddz = (w[1] == 0) && (w[3] == 0) && (w[5] == 0) && (w[7] == 0);
  unsigned long long wa = __ballot(!oddz);
  if ((t & 63) == 0) wres[t >> 6] = (wa == 0ull);
  __syncthreads();
  int is64 = 1;
#pragma unroll
  for (int i = 0; i < 16; i++) is64 &= wres[i];

  int bits = 0, cnt = 0;
  if (is64) {
    const long long* l64 = (const long long*)labels;
#pragma unroll
    for (int j = 0; j < 8; j++) {
      bool f = (l64[base + j] == 2ll);
      bits |= ((int)f) << j;
      cnt += (int)f;
    }
  } else {
#pragma unroll
    for (int j = 0; j < 8; j++) {
      bool f = (w[j] == 2);
      bits |= ((int)f) << j;
      cnt += (int)f;
    }
  }
  sc[t] = cnt;
  __syncthreads();
  for (int off = 1; off < 1024; off <<= 1) {
    int v = 0;
    if (t >= off) v = sc[t - off];
    __syncthreads();
    sc[t] += v;
    __syncthreads();
  }
  int pos = sc[t] - cnt;  // exclusive prefix
#pragma unroll
  for (int j = 0; j < 8; j++) {
    if (bits & (1 << j)) idx[pos++] = base + j;
  }
  if (t == 1023) *Lout = sc[1023];
}

// one wave per compact slot: normalize features, gather coords, diag flag
__global__ __launch_bounds__(256) void k_gather(const float* __restrict__ feats,
                                                const float* __restrict__ coords,
                                                const int* __restrict__ idx,
                                                const int* __restrict__ Lp,
                                                float* __restrict__ fnT,
                                                float4* __restrict__ cs,
                                                int* __restrict__ diagf) {
  const int L = *Lp;
  const int gw = (int)((blockIdx.x * blockDim.x + threadIdx.x) >> 6);
  const int lane = threadIdx.x & 63;
  if (gw >= L) return;
  const int row = idx[gw];
  float f = feats[row * DIM + lane];
  float ss = f * f;
#pragma unroll
  for (int m = 32; m; m >>= 1) ss += __shfl_xor(ss, m);
  float nrm = fmaxf(sqrtf(ss), 1e-8f);
  fnT[lane * NPTS + gw] = f / nrm;  // transposed store
  if (lane == 0) {
    float c0 = coords[row * 3 + 0];
    float c1 = coords[row * 3 + 1];
    float c2 = coords[row * 3 + 2];
    float p0 = __fmul_rn(c0, c0);
    float p1 = __fmul_rn(c1, c1);
    float p2 = __fmul_rn(c2, c2);
    float s = __fadd_rn(__fadd_rn(p0, p1), p2);
    float g = __fadd_rn(__fadd_rn(p0, p2), p1);
    diagf[gw] = (__fadd_rn(s, -g) > 5e-13f) ? 1 : 0;
    cs[gw] = make_float4(c0, c1, c2, c0 * c0 + c1 * c1 + c2 * c2);
  }
}

__global__ __launch_bounds__(256, 5) void k_pair(const float* __restrict__ fnT,
                                                 const float4* __restrict__ cs,
                                                 const int* __restrict__ Lp,
                                                 const int* __restrict__ diagf,
                                                 float* __restrict__ pp,
                                                 float* __restrict__ pn,
                                                 float* __restrict__ contp) {
  __shared__ float Ak[DIM][TILE];
  __shared__ float Bk[DIM][TILE];
  __shared__ float cred[4];

  const int L = *Lp;
  const int nT = (L + TILE - 1) / TILE;
  const int bx = blockIdx.x, ch = blockIdx.y;
  const int t = threadIdx.x;
  const int tr = t >> 4;  // 0..15 -> 4-row group
  const int tc = t & 15;  // 0..15 -> 4-col group
  float cont = 0.f;

  for (int bi = bx; bi < nT; bi += GX) {
    const int rb = bi * TILE;
    __syncthreads();  // prior iteration's reads of Ak done
    // ---- stage A tile: Ak[k][r] from fnT[k][rb+r], zero-fill r>=L ----
#pragma unroll
    for (int i = 0; i < 4; i++) {
      int q = t + 256 * i;  // 0..1023 float4 units
      int k = q >> 4;       // 0..63
      int c0 = (q & 15) * 4;
      float4 v = *(const float4*)&fnT[k * NPTS + rb + c0];
      if (rb + c0 + 0 >= L) v.x = 0.f;
      if (rb + c0 + 1 >= L) v.y = 0.f;
      if (rb + c0 + 2 >= L) v.z = 0.f;
      if (rb + c0 + 3 >= L) v.w = 0.f;
      *(float4*)&Ak[k][c0] = v;
    }

    float4 ca[4];
    int dfr[4];
#pragma unroll
    for (int ri = 0; ri < 4; ri++) {
      int ig = rb + tr * 4 + ri;
      ca[ri] = cs[ig];
      dfr[ri] = diagf[ig];
    }

    float pos_r[4] = {0.f, 0.f, 0.f, 0.f};
    float neg_r[4] = {0.f, 0.f, 0.f, 0.f};

    for (int jt = ch; jt < nT; jt += CHUNKS) {
      const int cb = jt * TILE;
      __syncthreads();  // prior compute done before Bk overwrite
#pragma unroll
      for (int i = 0; i < 4; i++) {
        int q = t + 256 * i;
        int k = q >> 4;
        int c0 = (q & 15) * 4;
        float4 v = *(const float4*)&fnT[k * NPTS + cb + c0];
        if (cb + c0 + 0 >= L) v.x = 0.f;
        if (cb + c0 + 1 >= L) v.y = 0.f;
        if (cb + c0 + 2 >= L) v.z = 0.f;
        if (cb + c0 + 3 >= L) v.w = 0.f;
        *(float4*)&Bk[k][c0] = v;
      }
      __syncthreads();

      float acc[4][4];
#pragma unroll
      for (int ri = 0; ri < 4; ri++)
#pragma unroll
        for (int ci = 0; ci < 4; ci++) acc[ri][ci] = 0.f;

#pragma unroll 8
      for (int k = 0; k < DIM; k++) {
        float4 a = *(const float4*)&Ak[k][tr * 4];
        float4 b = *(const float4*)&Bk[k][tc * 4];
        float av[4] = {a.x, a.y, a.z, a.w};
        float bv[4] = {b.x, b.y, b.z, b.w};
#pragma unroll
        for (int ri = 0; ri < 4; ri++)
#pragma unroll
          for (int ci = 0; ci < 4; ci++) acc[ri][ci] += av[ri] * bv[ci];
      }

      // epilogue: exp / distance / masked accumulation
#pragma unroll
      for (int ci = 0; ci < 4; ci++) {
        int jg = cb + tc * 4 + ci;
        float4 cbv = cs[jg];
        bool jv = (jg < L);
#pragma unroll
        for (int ri = 0; ri < 4; ri++) {
          int ig = rb + tr * 4 + ri;
          bool valid = jv && (ig < L);
          float sim = acc[ri][ci];
          float4 cav = ca[ri];
          float d3 = cav.x * cbv.x + cav.y * cbv.y + cav.z * cbv.z;
          float sq = fmaxf(cav.w + cbv.w - 2.f * d3, 0.f);
          bool within = (sq < 1.0f) && (sq > 1e-12f);
          if (ig == jg) within = (dfr[ri] != 0);  // ref diagonal semantics
          float e = __expf(sim * 10.f);
          if (valid) {
            if (within) {
              pos_r[ri] += e;
              cont += fabsf(1.f - sim - sqrtf(sq));
            } else {
              neg_r[ri] += e;
            }
          }
        }
      }
    }

    // reduce pos/neg across the 16 tc lanes (lane bits 0..3)
#pragma unroll
    for (int ri = 0; ri < 4; ri++) {
      float p = pos_r[ri], n = neg_r[ri];
#pragma unroll
      for (int m = 1; m < 16; m <<= 1) {
        p += __shfl_xor(p, m);
        n += __shfl_xor(n, m);
      }
      if (tc == 0) {
        int ig = rb + tr * 4 + ri;
        pp[ch * NPTS + ig] = p;
        pn[ch * NPTS + ig] = n;
      }
    }
  }

  // continuity: block reduce (accumulated over all bi, jt)
#pragma unroll
  for (int m = 1; m < 64; m <<= 1) cont += __shfl_xor(cont, m);
  if ((t & 63) == 0) cred[t >> 6] = cont;
  __syncthreads();
  if (t == 0) contp[bx * CHUNKS + ch] = cred[0] + cred[1] + cred[2] + cred[3];
}

__global__ __launch_bounds__(1024) void k_final(const float* __restrict__ pp,
                                                const float* __restrict__ pn,
                                                const float* __restrict__ contp,
                                                const int* __restrict__ Lp,
                                                float* __restrict__ out) {
  __shared__ float red[32];
  const int L = *Lp;
  const int t = threadIdx.x;
  float accI = 0.f;
  for (int s = t; s < L; s += 1024) {
    float pos = 0.f, neg = 0.f;
#pragma unroll
    for (int c = 0; c < CHUNKS; c++) {
      pos += pp[c * NPTS + s];
      neg += pn[c * NPTS + s];
    }
    accI += -logf(pos / (neg + pos + 1e-6f));
  }
  float accC = 0.f;
  for (int c = t; c < NCT; c += 1024) accC += contp[c];
#pragma unroll
  for (int m = 1; m < 64; m <<= 1) {
    accI += __shfl_xor(accI, m);
    accC += __shfl_xor(accC, m);
  }
  if ((t & 63) == 0) {
    red[t >> 6] = accI;
    red[16 + (t >> 6)] = accC;
  }
  __syncthreads();
  if (t == 0) {
    float sI = 0.f, sC = 0.f;
#pragma unroll
    for (int w = 0; w < 16; w++) {
      sI += red[w];
      sC += red[16 + w];
    }
    float fL = (float)L;
    out[0] = sI / fL + 0.5f * (sC / (fL * fL));
  }
}

extern "C" void kernel_launch(void* const* d_in, const int* in_sizes, int n_in,
                              void* d_out, int out_size, void* d_ws, size_t ws_size,
                              hipStream_t stream) {
  const float* features = (const float*)d_in[0];
  const int* labels = (const int*)d_in[1];
  const float* coords = (const float*)d_in[2];

  char* ws = (char*)d_ws;
  int* Lp = (int*)(ws + OFF_L);
  int* idx = (int*)(ws + OFF_IDX);
  float* fnT = (float*)(ws + OFF_FNT);
  float4* cs = (float4*)(ws + OFF_CS);
  float* pp = (float*)(ws + OFF_PP);
  float* pn = (float*)(ws + OFF_PN);
  float* contp = (float*)(ws + OFF_CT);
  int* diagf = (int*)(ws + OFF_DF);
  float* out = (float*)d_out;

  k_scan<<<1, 1024, 0, stream>>>(labels, idx, Lp);
  k_gather<<<(NPTS * 64) / 256, 256, 0, stream>>>(features, coords, idx, Lp, fnT, cs, diagf);
  k_pair<<<dim3(GX, CHUNKS), 256, 0, stream>>>(fnT, cs, Lp, diagf, pp, pn, contp);
  k_final<<<1, 1024, 0, stream>>>(pp, pn, contp, Lp, out);
}